// Round 9
// baseline (284.518 us; speedup 1.0000x reference)
//
#include <hip/hip_runtime.h>
#include <hip/hip_fp16.h>

// CSR scatter/gather + spread-slot epilogue:
//   memset : zero 64 loss slot-pairs + counts + cursors (~12KB)
//   count  : conn pass -> counts[chunk][bucket] (LDS hist + atomic merge)
//   fill   : block owns 4096 elems. Local wave-scan of counts -> global CSR
//            base (no scan kernel); compute force once per element (8 pred
//            gathers in flight); one cursor atomic per (block,bucket);
//            two LDS-sorted coalesced flush stages into bucket-major lists.
//            Records: 8B {fx16,fy16 | local16,fz16}.
//   accum  : block per 1024-node bucket; derives list offset by reducing
//            counts[0..b-1] (L2-hot); dense coalesced record replay into LDS
//            fp32 tile; last chunk fuses masked loss into 64 line-padded
//            slot pairs (b&63) -- no same-address far atomics.
//   final  : 1 wave reduces 64 slots, divides, writes out[0].
// K element-chunks + fp16 F_int partial picked from ws_size (K=1 preferred).

#define SPAN   1024
#define NBMAX  1024
#define CEPB   8        // count: elems/thread
#define FTH    1024     // fill threads
#define FBE    4096     // elems per fill block
#define ATH    512      // accum threads

struct F3 { float x, y, z; };

__device__ __forceinline__ uint2 packrec(float fx, float fy, float fz, int local) {
    unsigned short hx = __half_as_ushort(__float2half(fx));
    unsigned short hy = __half_as_ushort(__float2half(fy));
    unsigned short hz = __half_as_ushort(__float2half(fz));
    return make_uint2(((unsigned)hy << 16) | hx, ((unsigned)local << 16) | hz);
}

// 1024-thread inclusive scan. Call sites separated by __syncthreads().
__device__ __forceinline__ int block_incl_scan(int v, int* wsum, int lane, int wv) {
    #pragma unroll
    for (int off = 1; off < 64; off <<= 1) {
        int t = __shfl_up(v, off, 64);
        if (lane >= off) v += t;
    }
    if (lane == 63) wsum[wv] = v;
    __syncthreads();
    if (wv == 0) {
        int w = (lane < 16) ? wsum[lane] : 0;
        #pragma unroll
        for (int off = 1; off < 16; off <<= 1) {
            int t = __shfl_up(w, off, 64);
            if (lane >= off) w += t;
        }
        if (lane < 16) wsum[lane] = w;
    }
    __syncthreads();
    return v + ((wv > 0) ? wsum[wv - 1] : 0);
}

__global__ void __launch_bounds__(1024)
count_kernel(const int2* __restrict__ conn, int* __restrict__ counts,
             int E, int chunkElems, int slabsPC, int NB) {
    __shared__ int hist[NBMAX];
    int c = blockIdx.x / slabsPC;
    int s = blockIdx.x - c * slabsPC;
    int base = c * chunkElems + s * (1024 * CEPB);
    int end  = (c + 1) * chunkElems;
    if (end > E) end = E;

    hist[threadIdx.x] = 0;
    __syncthreads();

    #pragma unroll
    for (int i = 0; i < CEPB; ++i) {
        int e = base + i * 1024 + threadIdx.x;
        if (e < end) {
            int2 cn = conn[e];
            atomicAdd(&hist[cn.x >> 10], 1);
            atomicAdd(&hist[cn.y >> 10], 1);
        }
    }
    __syncthreads();

    int* cc = counts + (size_t)c * NB;
    if (threadIdx.x < NB) {
        int h = hist[threadIdx.x];
        if (h) atomicAdd(&cc[threadIdx.x], h);
    }
}

__global__ void __launch_bounds__(1024)
fill_kernel(const int2* __restrict__ conn,
            const F3*  __restrict__ pred,
            const float* __restrict__ u_c,
            const float* __restrict__ theta_c,
            const float* __restrict__ len,
            const float* __restrict__ pE,
            const float* __restrict__ pA,
            const float* __restrict__ pI,
            const float* __restrict__ dir,
            const int* __restrict__ counts_c,
            int* __restrict__ cursor_c,          // zero-initialized row
            uint2* __restrict__ lists,
            int cs, int ce, int NB) {
    __shared__ uint2          slab[FBE];
    __shared__ unsigned short sbk [FBE];
    __shared__ int hist [NBMAX];
    __shared__ int hist2[NBMAX];
    __shared__ int boff [NBMAX];
    __shared__ int sc   [NBMAX];
    __shared__ int gpos [NBMAX];
    __shared__ int wsum [16];

    int tid = threadIdx.x, lane = tid & 63, wv = tid >> 6;

    hist[tid] = 0; hist2[tid] = 0;
    int cval = (tid < NB) ? counts_c[tid] : 0;
    int inc  = block_incl_scan(cval, wsum, lane, wv);
    boff[tid] = inc - cval;

    float uc = u_c[0];
    float tc = theta_c[0];
    int bs = cs + blockIdx.x * FBE;
    int be = bs + FBE; if (be > ce) be = ce;

    unsigned sv[8];
    uint2    rc[8];

    #pragma unroll
    for (int j = 0; j < 4; ++j) {
        int e = bs + j * FTH + tid;
        unsigned sa = 0xFFFFFFFFu, sb = 0xFFFFFFFFu;
        if (e < be) {
            int2 cn = conn[e];
            int na = cn.x, nb = cn.y;

            F3 pa_ = pred[na];
            F3 pb_ = pred[nb];

            float c  = dir[3 * e + 0];
            float s  = dir[3 * e + 2];
            float L  = len[e];
            float Ee = pE[e];
            float EA = Ee * pA[e];
            float EI = Ee * pI[e];

            float a0 = pa_.x * uc;
            float a1 = pa_.y * uc;
            float a2 = pa_.z * tc;
            float b0 = pb_.x * uc;
            float b1 = pb_.y * uc;
            float b2 = pb_.z * tc;

            float u_A  =  c * a0 + s * a1;
            float w_A  = -s * a0 + c * a1;
            float th_A = -a2;
            float u_B  =  c * b0 + s * b1;
            float w_B  = -s * b0 + c * b1;
            float th_B = -b2;

            float invL  = 1.0f / L;
            float ea_l  = EA * invL;             // AXIAL_WEIGHT = 1.0
            float ei_l  = EI * invL;
            float ei_l2 = ei_l  * invL;
            float ei_l3 = ei_l2 * invL;

            float dw = w_A - w_B;
            float f0 = ea_l * (u_A - u_B);
            float f1 = 12.0f * ei_l3 * dw + 6.0f * ei_l2 * (th_A + th_B);
            float f2 = 6.0f * ei_l2 * dw + 4.0f * ei_l * th_A + 2.0f * ei_l * th_B;
            float f5 = 6.0f * ei_l2 * dw + 2.0f * ei_l * th_A + 4.0f * ei_l * th_B;

            float fA0 = c * f0 - s * f1;
            float fA1 = s * f0 + c * f1;

            int* h = (j < 2) ? hist : hist2;

            int bkA = na >> 10;
            int rA  = atomicAdd(&h[bkA], 1);
            sa = ((unsigned)rA << 10) | (unsigned)bkA;
            rc[2 * j + 0] = packrec(fA0, fA1, -f2, na & 1023);

            int bkB = nb >> 10;
            int rB  = atomicAdd(&h[bkB], 1);
            sb = ((unsigned)rB << 10) | (unsigned)bkB;
            rc[2 * j + 1] = packrec(-fA0, -fA1, -f5, nb & 1023);
        }
        sv[2 * j + 0] = sa;
        sv[2 * j + 1] = sb;
    }
    __syncthreads();

    // one cursor reservation per (block,bucket)
    if (tid < NB) {
        int tot = hist[tid] + hist2[tid];
        gpos[tid] = tot ? (boff[tid] + atomicAdd(&cursor_c[tid], tot)) : 0;
    }

    // ---- stage 0 ----
    int i0 = block_incl_scan(hist[tid], wsum, lane, wv);
    sc[tid] = i0;
    __syncthreads();
    #pragma unroll
    for (int r = 0; r < 4; ++r) {
        unsigned s2 = sv[r];
        if (s2 != 0xFFFFFFFFu) {
            int bk = (int)(s2 & 1023u);
            int rk = (int)(s2 >> 10);
            int slot = sc[bk] - hist[bk] + rk;
            slab[slot] = rc[r];
            sbk[slot]  = (unsigned short)bk;
        }
    }
    __syncthreads();
    int tot0 = sc[NBMAX - 1];
    for (int i = tid; i < tot0; i += FTH) {
        int bk = sbk[i];
        lists[gpos[bk] + (i - (sc[bk] - hist[bk]))] = slab[i];
    }
    __syncthreads();

    // ---- stage 1 ----
    int i1 = block_incl_scan(hist2[tid], wsum, lane, wv);
    sc[tid] = i1;
    __syncthreads();
    #pragma unroll
    for (int r = 4; r < 8; ++r) {
        unsigned s2 = sv[r];
        if (s2 != 0xFFFFFFFFu) {
            int bk = (int)(s2 & 1023u);
            int rk = (int)(s2 >> 10);
            int slot = sc[bk] - hist2[bk] + rk;
            slab[slot] = rc[r];
            sbk[slot]  = (unsigned short)bk;
        }
    }
    __syncthreads();
    int tot1 = sc[NBMAX - 1];
    for (int i = tid; i < tot1; i += FTH) {
        int bk = sbk[i];
        lists[gpos[bk] + hist[bk] + (i - (sc[bk] - hist2[bk]))] = slab[i];
    }
}

__global__ void __launch_bounds__(512)
accum_kernel(const uint2* __restrict__ lists,
             const int* __restrict__ counts_c,
             const float* __restrict__ Fext,
             const float* __restrict__ bcd,
             const float* __restrict__ bcr,
             double* __restrict__ accSlots,
             __half* __restrict__ fint16,
             int N, int isFirst, int isLast) {
    __shared__ float tile[SPAN * 3];
    __shared__ int ssum[8];
    __shared__ double sn[8], sd[8];

    int tid = threadIdx.x, lane = tid & 63, wv = tid >> 6;
    int b = blockIdx.x;
    int nodeLo = b * SPAN;
    int gBase = nodeLo * 3;
    int gMax  = 3 * N;

    // own list offset: reduce counts[0..b-1] (L2-hot 4KB row)
    int p = 0;
    for (int i = tid; i < b; i += ATH) p += counts_c[i];
    #pragma unroll
    for (int off = 32; off > 0; off >>= 1) p += __shfl_down(p, off, 64);
    if (lane == 0) ssum[wv] = p;

    if (isFirst) {
        for (int i = tid; i < SPAN * 3; i += ATH) tile[i] = 0.0f;
    } else {
        for (int i = tid; i < SPAN * 3; i += ATH) {
            int g = gBase + i;
            tile[i] = (g < gMax) ? __half2float(fint16[g]) : 0.0f;
        }
    }
    __syncthreads();

    int base = 0;
    #pragma unroll
    for (int w = 0; w < 8; ++w) base += ssum[w];

    int cnt = counts_c[b];
    const uint2* L = lists + base;
    for (int r = tid; r < cnt; r += ATH) {
        uint2 rec = L[r];
        float fx = __half2float(__ushort_as_half((unsigned short)(rec.x & 0xFFFFu)));
        float fy = __half2float(__ushort_as_half((unsigned short)(rec.x >> 16)));
        float fz = __half2float(__ushort_as_half((unsigned short)(rec.y & 0xFFFFu)));
        int local = (int)(rec.y >> 16);
        atomicAdd(&tile[local * 3 + 0], fx);
        atomicAdd(&tile[local * 3 + 1], fy);
        atomicAdd(&tile[local * 3 + 2], fz);
    }
    __syncthreads();

    if (!isLast) {
        for (int i = tid; i < SPAN * 3; i += ATH) {
            int g = gBase + i;
            if (g < gMax) fint16[g] = __float2half(tile[i]);
        }
        return;
    }

    // fused masked loss over this bucket's node range
    int spanCnt = N - nodeLo;
    if (spanCnt > SPAN) spanCnt = SPAN;

    double num = 0.0, den = 0.0;
    for (int l = tid; l < spanCnt; l += ATH) {
        int n = nodeLo + l;
        float md = 1.0f - bcd[n];
        float mr = 1.0f - bcr[n];
        float e0 = Fext[3 * n + 0];
        float e1 = Fext[3 * n + 1];
        float e2 = Fext[3 * n + 2];
        float r0 = (tile[l * 3 + 0] - e0) * md;
        float r1 = (tile[l * 3 + 1] - e1) * md;
        float r2 = (tile[l * 3 + 2] - e2) * mr;
        float g0 = e0 * md;
        float g1 = e1 * md;
        float g2 = e2 * mr;
        num += (double)r0 * r0 + (double)r1 * r1 + (double)r2 * r2;
        den += (double)g0 * g0 + (double)g1 * g1 + (double)g2 * g2;
    }
    #pragma unroll
    for (int off = 32; off > 0; off >>= 1) {
        num += __shfl_down(num, off, 64);
        den += __shfl_down(den, off, 64);
    }
    if (lane == 0) { sn[wv] = num; sd[wv] = den; }
    __syncthreads();
    if (tid == 0) {
        double tn = 0.0, td = 0.0;
        #pragma unroll
        for (int w = 0; w < 8; ++w) { tn += sn[w]; td += sd[w]; }
        // spread over 64 line-padded slot pairs: max ~16 same-line RMWs
        double* slot = accSlots + (size_t)(b & 63) * 8;
        atomicAdd(&slot[0], tn);
        atomicAdd(&slot[1], td);
    }
}

__global__ void final_kernel(const double* __restrict__ accSlots,
                             float* __restrict__ out) {
    int t = threadIdx.x;   // 64 threads
    double n = accSlots[t * 8 + 0];
    double d = accSlots[t * 8 + 1];
    #pragma unroll
    for (int off = 32; off > 0; off >>= 1) {
        n += __shfl_down(n, off, 64);
        d += __shfl_down(d, off, 64);
    }
    if (t == 0) {
        if (d < 1e-30) d = 1e-30;
        out[0] = (float)(n / d);
    }
}

static inline size_t align256(size_t x) { return (x + 255) & ~(size_t)255; }

extern "C" void kernel_launch(void* const* d_in, const int* in_sizes, int n_in,
                              void* d_out, int out_size, void* d_ws, size_t ws_size,
                              hipStream_t stream) {
    const F3*    pred    = (const F3*)d_in[0];
    const float* u_c     = (const float*)d_in[1];
    const float* theta_c = (const float*)d_in[2];
    const float* len     = (const float*)d_in[3];
    const float* pE      = (const float*)d_in[4];
    const float* pA      = (const float*)d_in[5];
    const float* pI      = (const float*)d_in[6];
    const float* dir     = (const float*)d_in[7];
    const float* Fext    = (const float*)d_in[8];
    const float* bcd     = (const float*)d_in[9];
    const float* bcr     = (const float*)d_in[10];
    const int2*  conn    = (const int2*)d_in[11];

    int N = in_sizes[0] / 3;
    int E = in_sizes[3];
    int NB = (N + SPAN - 1) / SPAN;   // must be <= NBMAX

    // Config ladder: K chunks; fp16 F_int partial when K>1
    const int cfgK[4] = {1, 2, 4, 8};
    int K = 8;
    size_t oF = 0, oL = 0, metaSz = 0;
    for (int t = 0; t < 4; ++t) {
        int Kc = cfgK[t];
        int ce = (E + Kc - 1) / Kc;
        size_t meta = 4096 + (size_t)2 * Kc * NB * 4;   // slots + counts + cursors
        size_t oFt  = align256(meta);
        size_t fb   = (Kc > 1) ? (size_t)3 * N * 2 : 0;
        size_t oLt  = align256(oFt + fb);
        size_t need = oLt + (size_t)2 * ce * 8;
        if (need <= ws_size || t == 3) {
            K = Kc; oF = oFt; oL = oLt; metaSz = meta;
            if (need <= ws_size) break;
        }
    }

    int chunkElems = (E + K - 1) / K;

    double* accSlots = (double*)d_ws;                     // 64 pairs * 64B
    int*    counts   = (int*)((char*)d_ws + 4096);
    int*    cursors  = counts + (size_t)K * NB;
    __half* fint16   = (__half*)((char*)d_ws + oF);
    uint2*  lists    = (uint2*)((char*)d_ws + oL);

    // zero slots + counts + cursors
    hipMemsetAsync(d_ws, 0, metaSz, stream);

    int slabsPC = (chunkElems + 1024 * CEPB - 1) / (1024 * CEPB);
    count_kernel<<<K * slabsPC, 1024, 0, stream>>>(conn, counts, E, chunkElems, slabsPC, NB);

    for (int c = 0; c < K; ++c) {
        int cs = c * chunkElems;
        if (cs >= E) break;
        int ce = cs + chunkElems;
        if (ce > E) ce = E;
        int nfb = (ce - cs + FBE - 1) / FBE;

        fill_kernel<<<nfb, FTH, 0, stream>>>(
            conn, pred, u_c, theta_c, len, pE, pA, pI, dir,
            counts + (size_t)c * NB, cursors + (size_t)c * NB,
            lists, cs, ce, NB);

        int isFirst = (c == 0);
        int isLast  = (ce == E);
        accum_kernel<<<NB, ATH, 0, stream>>>(
            lists, counts + (size_t)c * NB,
            Fext, bcd, bcr, accSlots, fint16, N, isFirst, isLast);
    }

    final_kernel<<<1, 64, 0, stream>>>(accSlots, (float*)d_out);
}